// Round 4
// baseline (116.947 us; speedup 1.0000x reference)
//
#include <hip/hip_runtime.h>

// Depth-4 path signature of [64,512,10] fp32 via time-split Chen scan.
// R4: (i,j)-PREFIX lanes. One lane owns {a1, a2[ij], a3[ij*], a4[ij**]} =
// 112 fp32 of state; per step ~130 FMA + 3 broadcast LDS reads (row) +
// 0.5 lane-indexed LDS reads (dx_i, dx_j as float4/4-steps). No reliance
// on SMEM scalarization. dx computed in-kernel from path (no dx pass).
//  K1 sig_group_kernel: 64 b x 8 g blocks (128 thr), 64 steps each,
//      writes group signature to ws (level-4 at padded offset 1112).
//  K2 combine_kernel: 64 blocks fold the 8 group sigs via Chen.

#define CH     10
#define LEN    512
#define NB     64
#define GROUPS 8
#define SPG    64              // steps/group (s=511 padded with dx=0)
#define SIGSZ  11110           // output: 10 + 100 + 1000 + 10000
#define SIGW   11112           // ws sig: level4 at 1112 (16B aligned)
#define L4W    1112
#define TSTR   68              // transposed LDS stride

__global__ __launch_bounds__(128, 1)
void sig_group_kernel(const float* __restrict__ path, float* __restrict__ wsig) {
    __shared__ __align__(16) float rowL[SPG * 12];   // dx rows, padded to 12
    __shared__ __align__(16) float dxT[CH * TSTR];   // transposed dx
    const int tid = threadIdx.x;
    const int b   = blockIdx.x >> 3;
    const int g   = blockIdx.x & 7;
    const int s0  = g * SPG;

    // ---- compute this group's increments straight from path ----
    const float* __restrict__ pb = path + b * (LEN * CH);
    for (int e = tid; e < SPG * CH; e += 128) {
        int s = e / CH, c = e - s * CH;
        int gs = s0 + s;
        const float* p = pb + gs * CH + c;
        float nxt = p[(gs < LEN - 1) ? CH : 0];      // clamp: never OOB
        float v = (gs < LEN - 1) ? (nxt - p[0]) : 0.f;
        rowL[s * 12 + c] = v;
        dxT[c * TSTR + s] = v;
    }
    __syncthreads();

    const int ij = (tid < 100) ? tid : tid - 28;     // dup lanes: benign
    const int i = ij / 10, j = ij % 10;

    float a1 = 0.f, a2 = 0.f, a3[10], a4[100];
    #pragma unroll
    for (int k = 0; k < 10; ++k) a3[k] = 0.f;
    #pragma unroll
    for (int m = 0; m < 100; ++m) a4[m] = 0.f;

    for (int s4 = 0; s4 < SPG; s4 += 4) {
        const float4 di4 = *(const float4*)(dxT + i * TSTR + s4);
        const float4 dj4 = *(const float4*)(dxT + j * TSTR + s4);
        #pragma unroll
        for (int u = 0; u < 4; ++u) {
            const float* row = rowL + (s4 + u) * 12;
            const float4 ra = *(const float4*)(row);
            const float4 rb = *(const float4*)(row + 4);
            const float2 rc = *(const float2*)(row + 8);
            const float r_[10] = {ra.x, ra.y, ra.z, ra.w,
                                  rb.x, rb.y, rb.z, rb.w, rc.x, rc.y};
            const float dxi = (&di4.x)[u];
            const float dxj = (&dj4.x)[u];

            const float p1 = fmaf(dxi, 1.f / 24.f, a1 * (1.f / 6.f));
            const float q1 = fmaf(dxi, 1.f / 6.f,  a1 * 0.5f);
            const float rr = fmaf(dxi, 0.5f, a1);
            const float p2 = fmaf(p1, dxj, a2 * 0.5f);
            const float q2 = fmaf(q1, dxj, a2);
            a2 = fmaf(rr, dxj, a2);
            a1 += dxi;

            #pragma unroll
            for (int k = 0; k < 10; ++k) {
                const float p3 = fmaf(p2, r_[k], a3[k]);
                a3[k] = fmaf(q2, r_[k], a3[k]);
                #pragma unroll
                for (int l = 0; l < 10; ++l)
                    a4[k * 10 + l] = fmaf(p3, r_[l], a4[k * 10 + l]);
            }
        }
    }

    float* wb = wsig + (b * GROUPS + g) * SIGW;
    float4* w4 = (float4*)(wb + L4W + ij * 100);     // 16B aligned
    #pragma unroll
    for (int m = 0; m < 25; ++m)
        w4[m] = make_float4(a4[4 * m], a4[4 * m + 1], a4[4 * m + 2], a4[4 * m + 3]);
    #pragma unroll
    for (int k = 0; k < 10; ++k) wb[110 + ij * 10 + k] = a3[k];
    wb[10 + ij] = a2;
    if (j == 0) wb[i] = a1;
}

__global__ __launch_bounds__(128, 1)
void combine_kernel(const float* __restrict__ wsig, float* __restrict__ out) {
    __shared__ float Bs[1110];                       // B1|B2|B3 of right factor
    const int tid = threadIdx.x;
    const int b   = blockIdx.x;
    const int ij  = (tid < 100) ? tid : tid - 28;
    const int i = ij / 10, j = ij % 10;

    const float* __restrict__ w0 = wsig + b * GROUPS * SIGW;
    float a1 = w0[i];
    float a2 = w0[10 + ij];
    float a3[10], a4[100];
    #pragma unroll
    for (int k = 0; k < 10; ++k) a3[k] = w0[110 + ij * 10 + k];
    {
        const float4* p4 = (const float4*)(w0 + L4W + ij * 100);
        #pragma unroll
        for (int m = 0; m < 25; ++m) {
            float4 v = p4[m];
            a4[4 * m] = v.x; a4[4 * m + 1] = v.y;
            a4[4 * m + 2] = v.z; a4[4 * m + 3] = v.w;
        }
    }

    for (int g = 1; g < GROUPS; ++g) {
        const float* __restrict__ wg = w0 + g * SIGW;
        __syncthreads();
        for (int e = tid; e < 1110; e += 128) Bs[e] = wg[e];
        __syncthreads();
        float b4[100];
        const float4* b4p = (const float4*)(wg + L4W + ij * 100);
        #pragma unroll
        for (int m = 0; m < 25; ++m) {
            float4 v = b4p[m];
            b4[4 * m] = v.x; b4[4 * m + 1] = v.y;
            b4[4 * m + 2] = v.z; b4[4 * m + 3] = v.w;
        }
        const float* B1 = Bs;
        const float* B2 = Bs + 10;
        const float* B3 = Bs + 110;
        #pragma unroll
        for (int k = 0; k < 10; ++k) {
            #pragma unroll
            for (int l = 0; l < 10; ++l)
                a4[k * 10 + l] += a3[k] * B1[l] + a2 * B2[k * 10 + l]
                                + a1 * B3[(j * 10 + k) * 10 + l] + b4[k * 10 + l];
        }
        #pragma unroll
        for (int k = 0; k < 10; ++k)
            a3[k] += a2 * B1[k] + a1 * B2[j * 10 + k] + B3[ij * 10 + k];
        a2 += a1 * B1[j] + B2[ij];
        a1 += B1[i];
    }

    float* ob = out + b * SIGSZ;
    float2* o4 = (float2*)(ob + 1110 + ij * 100);    // 8B aligned
    #pragma unroll
    for (int m = 0; m < 50; ++m)
        o4[m] = make_float2(a4[2 * m], a4[2 * m + 1]);
    #pragma unroll
    for (int k = 0; k < 10; ++k) ob[110 + ij * 10 + k] = a3[k];
    ob[10 + ij] = a2;
    if (j == 0) ob[i] = a1;
}

extern "C" void kernel_launch(void* const* d_in, const int* in_sizes, int n_in,
                              void* d_out, int out_size, void* d_ws, size_t ws_size,
                              hipStream_t stream) {
    const float* path = (const float*)d_in[0];   // [64,512,10] fp32
    float* out  = (float*)d_out;                 // [64,11110] fp32
    float* wsig = (float*)d_ws;                  // [64][8][11112] (~22.8 MB)

    sig_group_kernel<<<dim3(NB * GROUPS), dim3(128), 0, stream>>>(path, wsig);
    combine_kernel<<<dim3(NB), dim3(128), 0, stream>>>(wsig, out);
}

// Round 5
// 116.201 us; speedup vs baseline: 1.0064x; 1.0064x over previous
//
#include <hip/hip_runtime.h>

// Depth-4 path signature of [64,512,10] fp32 via time-split Chen scan.
// R5: prefix-lane (one lane owns (i,j): a1,a2,a3[10],a4[100]) with a
// spill-proof 1-step body (~127 FMA, fully unrolled, SROA-friendly) and
// explicit software pipelining of the LDS broadcast row + dxi/dxj reads.
//  K1 sig_group_kernel: 64 b x 8 g blocks (128 thr), 64 steps each.
//  K2 combine_kernel:   64 b x 5 k-part blocks fold 8 group sigs (Chen).

#define CH     10
#define LEN    512
#define NB     64
#define GROUPS 8
#define SPG    64              // steps/group (tail padded with dx=0)
#define SIGSZ  11110           // output: 10 + 100 + 1000 + 10000
#define SIGW   11112           // ws sig stride; level4 at 1112 (16B aligned)
#define L4W    1112
#define TSTR   68              // transposed LDS stride (floats)

__global__ __launch_bounds__(128, 1)
void sig_group_kernel(const float* __restrict__ path, float* __restrict__ wsig) {
    __shared__ __align__(16) float rowL[(SPG + 1) * 12];  // +1 step pad (zeros)
    __shared__ __align__(16) float dxT[CH * TSTR];        // transposed, s=0..64
    const int tid = threadIdx.x;
    const int b   = blockIdx.x >> 3;
    const int g   = blockIdx.x & 7;
    const int s0  = g * SPG;

    const float* __restrict__ pb = path + b * (LEN * CH);
    for (int e = tid; e < (SPG + 1) * CH; e += 128) {
        int s = e / CH, c = e - s * CH;
        int gs = s0 + s;
        float v = 0.f;
        if (s < SPG && gs < LEN - 1)
            v = pb[gs * CH + c + CH] - pb[gs * CH + c];
        rowL[s * 12 + c] = v;
        dxT[c * TSTR + s] = v;
    }
    __syncthreads();

    const int ij = (tid < 100) ? tid : tid - 28;   // dup lanes: benign
    const int i = ij / 10, j = ij % 10;

    float a1 = 0.f, a2 = 0.f, a3[10], a4[100];
    #pragma unroll
    for (int k = 0; k < 10; ++k) a3[k] = 0.f;
    #pragma unroll
    for (int m = 0; m < 100; ++m) a4[m] = 0.f;

    // preload step 0
    float4 ra = *(const float4*)(rowL);
    float4 rb = *(const float4*)(rowL + 4);
    float2 rc = *(const float2*)(rowL + 8);
    float dxi = dxT[i * TSTR];
    float dxj = dxT[j * TSTR];

    for (int s = 0; s < SPG; ++s) {
        // prefetch step s+1 (pad row s=64 is zeros; never OOB)
        const float* nrow = rowL + (s + 1) * 12;
        const float4 na = *(const float4*)(nrow);
        const float4 nb = *(const float4*)(nrow + 4);
        const float2 nc = *(const float2*)(nrow + 8);
        const float ndxi = dxT[i * TSTR + s + 1];
        const float ndxj = dxT[j * TSTR + s + 1];

        const float r0 = ra.x, r1 = ra.y, r2 = ra.z, r3 = ra.w;
        const float r4 = rb.x, r5 = rb.y, r6 = rb.z, r7 = rb.w;
        const float r8 = rc.x, r9 = rc.y;
        const float r_[10] = {r0, r1, r2, r3, r4, r5, r6, r7, r8, r9};

        const float p1 = fmaf(dxi, 1.f / 24.f, a1 * (1.f / 6.f));
        const float q1 = fmaf(dxi, 1.f / 6.f,  a1 * 0.5f);
        const float rr = fmaf(dxi, 0.5f, a1);
        const float p2 = fmaf(p1, dxj, a2 * 0.5f);
        const float q2 = fmaf(q1, dxj, a2);
        a2 = fmaf(rr, dxj, a2);
        a1 += dxi;

        #pragma unroll
        for (int k = 0; k < 10; ++k) {
            const float p3 = fmaf(p2, r_[k], a3[k]);
            a3[k] = fmaf(q2, r_[k], a3[k]);
            #pragma unroll
            for (int l = 0; l < 10; ++l)
                a4[k * 10 + l] = fmaf(p3, r_[l], a4[k * 10 + l]);
        }

        ra = na; rb = nb; rc = nc; dxi = ndxi; dxj = ndxj;
    }

    float* wb = wsig + (b * GROUPS + g) * SIGW;
    float4* w4 = (float4*)(wb + L4W + ij * 100);   // 16B aligned
    #pragma unroll
    for (int m = 0; m < 25; ++m)
        w4[m] = make_float4(a4[4 * m], a4[4 * m + 1], a4[4 * m + 2], a4[4 * m + 3]);
    #pragma unroll
    for (int k = 0; k < 10; ++k) wb[110 + ij * 10 + k] = a3[k];
    wb[10 + ij] = a2;
    if (j == 0) wb[i] = a1;
}

__global__ __launch_bounds__(128, 1)
void combine_kernel(const float* __restrict__ wsig, float* __restrict__ out) {
    __shared__ float Bs[1110];                  // B1|B2|B3 of right factor
    const int tid  = threadIdx.x;
    const int b    = blockIdx.x / 5;
    const int part = blockIdx.x % 5;            // level-4 k-pair: k0 = 2*part
    const int k0   = part * 2;
    const int ij = (tid < 100) ? tid : tid - 28;
    const int i = ij / 10, j = ij % 10;

    const float* __restrict__ w0 = wsig + b * GROUPS * SIGW;
    float a1 = w0[i];
    float a2 = w0[10 + ij];
    float a3[10], a4[20];
    #pragma unroll
    for (int k = 0; k < 10; ++k) a3[k] = w0[110 + ij * 10 + k];
    {
        const float2* p2 = (const float2*)(w0 + L4W + ij * 100 + k0 * 10);
        #pragma unroll
        for (int m = 0; m < 10; ++m) {
            float2 v = p2[m];
            a4[2 * m] = v.x; a4[2 * m + 1] = v.y;
        }
    }

    for (int g = 1; g < GROUPS; ++g) {
        const float* __restrict__ wg = w0 + g * SIGW;
        __syncthreads();                        // protect Bs reuse
        for (int e = tid; e < 1110; e += 128) Bs[e] = wg[e];
        __syncthreads();
        float b4[20];
        const float2* b2p = (const float2*)(wg + L4W + ij * 100 + k0 * 10);
        #pragma unroll
        for (int m = 0; m < 10; ++m) {
            float2 v = b2p[m];
            b4[2 * m] = v.x; b4[2 * m + 1] = v.y;
        }
        // level 4 (this part's two k rows), using OLD a1..a3
        #pragma unroll
        for (int kk = 0; kk < 2; ++kk) {
            const int k = k0 + kk;
            #pragma unroll
            for (int l = 0; l < 10; ++l)
                a4[kk * 10 + l] += a3[k] * Bs[l] + a2 * Bs[10 + k * 10 + l]
                                 + a1 * Bs[110 + (j * 10 + k) * 10 + l]
                                 + b4[kk * 10 + l];
        }
        // level 3 (full, uses OLD a1,a2)
        #pragma unroll
        for (int k = 0; k < 10; ++k)
            a3[k] += a2 * Bs[k] + a1 * Bs[10 + j * 10 + k] + Bs[110 + ij * 10 + k];
        a2 += a1 * Bs[j] + Bs[10 + ij];
        a1 += Bs[i];
    }

    float* ob = out + b * SIGSZ;
    float2* o2 = (float2*)(ob + 1110 + ij * 100 + k0 * 10);   // 8B aligned
    #pragma unroll
    for (int m = 0; m < 10; ++m)
        o2[m] = make_float2(a4[2 * m], a4[2 * m + 1]);
    if (part == 0) {
        #pragma unroll
        for (int k = 0; k < 10; ++k) ob[110 + ij * 10 + k] = a3[k];
        ob[10 + ij] = a2;
        if (j == 0) ob[i] = a1;
    }
}

extern "C" void kernel_launch(void* const* d_in, const int* in_sizes, int n_in,
                              void* d_out, int out_size, void* d_ws, size_t ws_size,
                              hipStream_t stream) {
    const float* path = (const float*)d_in[0];   // [64,512,10] fp32
    float* out  = (float*)d_out;                 // [64,11110] fp32
    float* wsig = (float*)d_ws;                  // [64][8][11112] (~22.8 MB)

    sig_group_kernel<<<dim3(NB * GROUPS), dim3(128), 0, stream>>>(path, wsig);
    combine_kernel<<<dim3(NB * 5), dim3(128), 0, stream>>>(wsig, out);
}